// Round 1
// baseline (78.939 us; speedup 1.0000x reference)
//
#include <hip/hip_runtime.h>

// CRF-RNN collapsed: out[t,i] = sum_j M[i,j] * orig[t,j],
//   orig[t,j] = sum_m inputs[t,j,m]*W_feat[m]
//   M = (I + B + B^2 + B^3) * diag(1/denom) + B^4
//   B[i,j] = 2*Kmat[i,j]/denom[i], Kmat[i,j] = sum_k kernels[i,j,k]*W_lin[k]
//   denom[i] = sum(W_feat) + 2*sum_j Kmat[i,j]

#define NREG 256   // N
#define KG   16    // gaussian kernels
#define MF   8     // features
#define BT   32    // t-rows per block in main kernel

// ---------------- K1: Kmat row, denom, B, Einv ----------------
__global__ __launch_bounds__(256) void k_prep(const float* __restrict__ kern,
                                              const float* __restrict__ Wlin,
                                              const float* __restrict__ Wfeat,
                                              float* __restrict__ B,
                                              float* __restrict__ Einv) {
    const int i = blockIdx.x, j = threadIdx.x;
    const float* kp = kern + ((size_t)i * NREG + j) * KG;
    float4 w0 = *(const float4*)(Wlin + 0);
    float4 w1 = *(const float4*)(Wlin + 4);
    float4 w2 = *(const float4*)(Wlin + 8);
    float4 w3 = *(const float4*)(Wlin + 12);
    float4 v0 = *(const float4*)(kp + 0);
    float4 v1 = *(const float4*)(kp + 4);
    float4 v2 = *(const float4*)(kp + 8);
    float4 v3 = *(const float4*)(kp + 12);
    float km = v0.x*w0.x + v0.y*w0.y + v0.z*w0.z + v0.w*w0.w
             + v1.x*w1.x + v1.y*w1.y + v1.z*w1.z + v1.w*w1.w
             + v2.x*w2.x + v2.y*w2.y + v2.z*w2.z + v2.w*w2.w
             + v3.x*w3.x + v3.y*w3.y + v3.z*w3.z + v3.w*w3.w;

    __shared__ float red[256];
    red[j] = km;
    __syncthreads();
    for (int s = 128; s > 0; s >>= 1) {
        if (j < s) red[j] += red[j + s];
        __syncthreads();
    }
    __shared__ float sden;
    if (j == 0) {
        float fw = 0.f;
#pragma unroll
        for (int m = 0; m < MF; ++m) fw += Wfeat[m];
        float den = fw + 2.f * red[0];
        sden = den;
        Einv[i] = 1.f / den;
    }
    __syncthreads();
    B[(size_t)i * NREG + j] = 2.f * km / sden;
}

// ---------------- generic 256x256 matmul body (Out = A*Bm) ----------------
__device__ __forceinline__ void mm_body(const float* __restrict__ A,
                                        const float* __restrict__ Bm,
                                        float* __restrict__ Out,
                                        int i0, int tid) {
    __shared__ float Ar[4][NREG];
#pragma unroll
    for (int r = 0; r < 4; ++r) Ar[r][tid] = A[(size_t)(i0 + r) * NREG + tid];
    __syncthreads();
    float acc0 = 0.f, acc1 = 0.f, acc2 = 0.f, acc3 = 0.f;
    for (int l = 0; l < NREG; l += 4) {
        float b0 = Bm[(size_t)(l + 0) * NREG + tid];
        float b1 = Bm[(size_t)(l + 1) * NREG + tid];
        float b2 = Bm[(size_t)(l + 2) * NREG + tid];
        float b3 = Bm[(size_t)(l + 3) * NREG + tid];
        float4 a0 = *(const float4*)&Ar[0][l];
        float4 a1 = *(const float4*)&Ar[1][l];
        float4 a2 = *(const float4*)&Ar[2][l];
        float4 a3 = *(const float4*)&Ar[3][l];
        acc0 += a0.x*b0 + a0.y*b1 + a0.z*b2 + a0.w*b3;
        acc1 += a1.x*b0 + a1.y*b1 + a1.z*b2 + a1.w*b3;
        acc2 += a2.x*b0 + a2.y*b1 + a2.z*b2 + a2.w*b3;
        acc3 += a3.x*b0 + a3.y*b1 + a3.z*b2 + a3.w*b3;
    }
    Out[(size_t)(i0 + 0) * NREG + tid] = acc0;
    Out[(size_t)(i0 + 1) * NREG + tid] = acc1;
    Out[(size_t)(i0 + 2) * NREG + tid] = acc2;
    Out[(size_t)(i0 + 3) * NREG + tid] = acc3;
}

// K2: C = B*B   (grid 64)
__global__ __launch_bounds__(256) void k_mm(const float* __restrict__ A,
                                            const float* __restrict__ Bm,
                                            float* __restrict__ Out) {
    mm_body(A, Bm, Out, blockIdx.x * 4, threadIdx.x);
}

// K3: G1 = B*C (blocks 0..63), G2 = C*C (blocks 64..127)
__global__ __launch_bounds__(256) void k_mm2(const float* __restrict__ B,
                                             const float* __restrict__ C,
                                             float* __restrict__ G1,
                                             float* __restrict__ G2) {
    const bool second = blockIdx.x >= 64;
    const float* A = second ? C : B;
    float* Out = second ? G2 : G1;
    mm_body(A, C, Out, (blockIdx.x & 63) * 4, threadIdx.x);
}

// K4: MT[j][i] = ((i==j) + B + C + G1)[i][j] * Einv[j] + G2[i][j]
__global__ __launch_bounds__(256) void k_comb(const float* __restrict__ B,
                                              const float* __restrict__ C,
                                              const float* __restrict__ G1,
                                              const float* __restrict__ G2,
                                              const float* __restrict__ Einv,
                                              float* __restrict__ MT) {
    const int i = blockIdx.x, j = threadIdx.x;
    const size_t idx = (size_t)i * NREG + j;
    float v = ((i == j) ? 1.f : 0.f) + B[idx] + C[idx] + G1[idx];
    v = v * Einv[j] + G2[idx];
    MT[(size_t)j * NREG + i] = v;
}

// ---------------- K5: fused feature-reduce + (T x N) * MT ----------------
__global__ __launch_bounds__(256) void k_main(const float* __restrict__ in,
                                              const float* __restrict__ Wfeat,
                                              const float* __restrict__ MT,
                                              float* __restrict__ out) {
    __shared__ float orig[BT][NREG];
    const int tid = threadIdx.x;
    const size_t t0 = (size_t)blockIdx.x * BT;

    float4 wa = *(const float4*)(Wfeat);
    float4 wb = *(const float4*)(Wfeat + 4);

    // stage 1: orig[tp][j] for this block's BT rows; 32B/lane coalesced loads
    const float4* in4 = (const float4*)in;
    for (int tp = 0; tp < BT; ++tp) {
        const size_t base = ((t0 + tp) * NREG + tid) * 2;  // float4 units
        float4 a = in4[base];
        float4 b = in4[base + 1];
        orig[tp][tid] = a.x*wa.x + a.y*wa.y + a.z*wa.z + a.w*wa.w
                      + b.x*wb.x + b.y*wb.y + b.z*wb.z + b.w*wb.w;
    }
    __syncthreads();

    // stage 2: out[t, i] = sum_j orig[t][j] * MT[j][i]
    // thread -> 4 i's (i4*4..i4*4+3) x 8 t's (tg..tg+7)
    const int i4 = tid & 63;
    const int tg = (tid >> 6) * 8;
    float4 acc[8];
#pragma unroll
    for (int t = 0; t < 8; ++t) acc[t] = make_float4(0.f, 0.f, 0.f, 0.f);

    const float4* MT4 = (const float4*)MT;
    for (int j = 0; j < NREG; j += 4) {
        float4 m0 = MT4[(size_t)(j + 0) * 64 + i4];
        float4 m1 = MT4[(size_t)(j + 1) * 64 + i4];
        float4 m2 = MT4[(size_t)(j + 2) * 64 + i4];
        float4 m3 = MT4[(size_t)(j + 3) * 64 + i4];
#pragma unroll
        for (int t = 0; t < 8; ++t) {
            float4 ov = *(const float4*)&orig[tg + t][j];
            acc[t].x += ov.x*m0.x + ov.y*m1.x + ov.z*m2.x + ov.w*m3.x;
            acc[t].y += ov.x*m0.y + ov.y*m1.y + ov.z*m2.y + ov.w*m3.y;
            acc[t].z += ov.x*m0.z + ov.y*m1.z + ov.z*m2.z + ov.w*m3.z;
            acc[t].w += ov.x*m0.w + ov.y*m1.w + ov.z*m2.w + ov.w*m3.w;
        }
    }

#pragma unroll
    for (int t = 0; t < 8; ++t) {
        ((float4*)(out + (t0 + tg + t) * NREG))[i4] = acc[t];
    }
}

extern "C" void kernel_launch(void* const* d_in, const int* in_sizes, int n_in,
                              void* d_out, int out_size, void* d_ws, size_t ws_size,
                              hipStream_t stream) {
    const float* inputs  = (const float*)d_in[0];  // (16384, 256, 8)
    const float* kernels = (const float*)d_in[1];  // (256, 256, 16)
    const float* Wfeat   = (const float*)d_in[2];  // (1, 8)
    const float* Wlin    = (const float*)d_in[3];  // (1, 16)
    float* out = (float*)d_out;                    // (16384, 256)

    float* ws   = (float*)d_ws;                    // needs ~1.32 MB
    float* B    = ws;                              // 65536
    float* C    = B  + NREG * NREG;                // 65536  (B^2)
    float* G1   = C  + NREG * NREG;                // 65536  (B^3)
    float* G2   = G1 + NREG * NREG;                // 65536  (B^4)
    float* Einv = G2 + NREG * NREG;                // 256
    float* MT   = Einv + NREG;                     // 65536  (M transposed)

    k_prep<<<256, 256, 0, stream>>>(kernels, Wlin, Wfeat, B, Einv);
    k_mm  <<<64,  256, 0, stream>>>(B, B, C);
    k_mm2 <<<128, 256, 0, stream>>>(B, C, G1, G2);
    k_comb<<<256, 256, 0, stream>>>(B, C, G1, G2, Einv, MT);
    k_main<<<16384 / BT, 256, 0, stream>>>(inputs, Wfeat, MT, out);
}